// Round 3
// baseline (8779.121 us; speedup 1.0000x reference)
//
#include <hip/hip_runtime.h>
#include <hip/hip_bf16.h>

// GRU: L=2, B=32, T=1024, H=512, OUT=512
// Round 3: W-in-registers (no LDS on the spine), in-band value|tag u32 h-state
// (no drain, no ordered canary), canary = cheap wake-up hint only, B-WG split
// into x-waves + h-waves with LDS partial exchange, gx prefetch depth-1.

typedef _Float16 f16x8 __attribute__((ext_vector_type(8)));
typedef float f32x4 __attribute__((ext_vector_type(4)));
typedef unsigned short u16;
typedef unsigned int u32;
typedef u32 u32x2 __attribute__((ext_vector_type(2)));
typedef u32 u32x4 __attribute__((ext_vector_type(4)));

#define MFMA16(a,b,c) __builtin_amdgcn_mfma_f32_16x16x32_f16((a),(b),(c),0,0,0)
#define SB0 __builtin_amdgcn_sched_barrier(0)
#define PERM_LO 0x05040100u
#define PERM_HI 0x07060302u

static constexpr int B = 32, T = 1024, H = 512, G3 = 1536;

// ws layout (bytes)
static constexpr size_t OFF_GX0    = 0;                                   // 96MB f16 [t][gate][u][b]
static constexpr size_t OFF_H0ALL  = OFF_GX0   + (size_t)T*B*G3*2;        // 64MB u32 [t][b][u] (value|tag)
static constexpr size_t OFF_H1RING = OFF_H0ALL + (size_t)T*B*H*4;         // 512KB u32 [8][b][u]
static constexpr size_t OFF_CAN    = OFF_H1RING + (size_t)8*B*H*4;        // 512KB: canA[1024][64], canB[1024][64]
static constexpr size_t OFF_WIH0   = OFF_CAN   + (size_t)2*1024*64*4;     // 1.5MB f16
static constexpr size_t OFF_H0I    = OFF_WIH0  + (size_t)G3*H*2;          // 32KB f16
static constexpr size_t OFF_H1I    = OFF_H0I   + (size_t)B*H*2;           // 32KB f16
static constexpr size_t OFF_H1F    = OFF_H1I   + (size_t)B*H*2;           // 64KB f32
// zero region each call: [OFF_H0ALL, OFF_WIH0)
static constexpr size_t ZERO_BYTES = OFF_WIH0 - OFF_H0ALL;                // 65MB

__device__ __forceinline__ u16 f2h(float x){ _Float16 h=(_Float16)x; return __builtin_bit_cast(u16,h); }
__device__ __forceinline__ float h2f(u16 u){ _Float16 h=__builtin_bit_cast(_Float16,u); return (float)h; }

// ---- coherent (device-scope) primitives ----
__device__ __forceinline__ u32 coh_load_u32(const u32* p){
  u32 r;
  asm volatile("global_load_dword %0, %1, off sc0 sc1\n\ts_waitcnt vmcnt(0)"
               : "=v"(r) : "v"(p) : "memory");
  return r;
}
__device__ __forceinline__ u32x4 coh_load_x4(const u32* p){   // NO waitcnt inside
  u32x4 r;
  asm volatile("global_load_dwordx4 %0, %1, off sc0 sc1" : "=v"(r) : "v"(p));
  return r;
}
__device__ __forceinline__ void coh_store_u32(u32* p, u32 v){
  asm volatile("global_store_dword %0, %1, off sc0 sc1" :: "v"(p), "v"(v) : "memory");
}
#define VMWAIT0 asm volatile("s_waitcnt vmcnt(0)" ::: "memory")

// cheap wake-up poll: 64 canaries in one coalesced 256B coherent read
__device__ __forceinline__ void poll64(const u32* base, u32 want, int lane){
  const u32* p = base + lane;
  while (!__all(coh_load_u32(p) == want)) {}
}

// self-validating tagged load of 16 A-fragments (8 u32 each) from row base hp.
// Retries (coherent) until every hi16 tag == ww's halves. Packs lo16 into f16x8.
__device__ __forceinline__ void tag_load16(f16x8* af, const u32* hp, u32 ww){
  for (;;){
    u32x4 q[32];
#pragma unroll
    for (int kk=0; kk<16; kk++){
      q[2*kk]   = coh_load_x4(hp + kk*32);
      q[2*kk+1] = coh_load_x4(hp + kk*32 + 4);
    }
    VMWAIT0; SB0;
    u32 diff = 0;
#pragma unroll
    for (int kk=0; kk<16; kk++){
      u32x4 a = q[2*kk], b = q[2*kk+1];
      diff |= (__builtin_amdgcn_perm(a[1],a[0],PERM_HI) ^ ww);
      diff |= (__builtin_amdgcn_perm(a[3],a[2],PERM_HI) ^ ww);
      diff |= (__builtin_amdgcn_perm(b[1],b[0],PERM_HI) ^ ww);
      diff |= (__builtin_amdgcn_perm(b[3],b[2],PERM_HI) ^ ww);
      u32x4 v;
      v[0] = __builtin_amdgcn_perm(a[1],a[0],PERM_LO);
      v[1] = __builtin_amdgcn_perm(a[3],a[2],PERM_LO);
      v[2] = __builtin_amdgcn_perm(b[1],b[0],PERM_LO);
      v[3] = __builtin_amdgcn_perm(b[3],b[2],PERM_LO);
      af[kk] = __builtin_bit_cast(f16x8, v);
    }
    if (__all(diff == 0)) break;
  }
}

// load 3x16 W fragments (f32 -> f16) into registers; col = cu, k = kk*32+lk*8
__device__ __forceinline__ void load_wf(f16x8 (*wf)[16], const float* Wbase, int cu, int lk){
#pragma unroll
  for (int g=0; g<3; g++)
#pragma unroll
    for (int kk=0; kk<16; kk++){
      const float* s = Wbase + ((size_t)(g*512 + cu))*H + kk*32 + lk*8;
      f32x4 s0 = *(const f32x4*)s, s1 = *(const f32x4*)(s+4);
      f16x8 v;
#pragma unroll
      for (int e=0; e<4; e++){ v[e] = (_Float16)s0[e]; v[4+e] = (_Float16)s1[e]; }
      wf[g][kk] = v;
    }
}

__device__ __forceinline__ void mm48(f32x4& R, f32x4& U, f32x4& N,
                                     const f16x8* af, const f16x8 (*wf)[16]){
#pragma unroll
  for (int kk=0; kk<16; kk++){
    R = MFMA16(af[kk], wf[0][kk], R);
    U = MFMA16(af[kk], wf[1][kk], U);
    N = MFMA16(af[kk], wf[2][kk], N);
  }
}

__device__ __forceinline__ float fsig(float x){ return 1.f/(1.f+__expf(-x)); }
__device__ __forceinline__ float ftanh(float x){
  x = fminf(15.f, fmaxf(-15.f, x));
  float e = __expf(-2.f*x);
  return (1.f-e)/(1.f+e);
}
__device__ __forceinline__ float gxval(u32x2 g, int j){
  u32 w = (j & 2) ? g[1] : g[0];
  return h2f((u16)(w >> ((j & 1) * 16)));
}

// ---------------- k0: prep (zero tag regions, convert weights/state) ----------------
__global__ __launch_bounds__(256) void k0_prep(const float* __restrict__ wih,
                                               const float* __restrict__ h0in,
                                               u16* __restrict__ wih0f16,
                                               u16* __restrict__ h0i,
                                               u16* __restrict__ h1i,
                                               u32x4* __restrict__ zbase){
  int i = blockIdx.x*256 + threadIdx.x;                  // 131072 threads
  const int NZ = (int)(ZERO_BYTES / 16);                 // u32x4 count
  u32x4 z; z[0]=0; z[1]=0; z[2]=0; z[3]=0;
  for (int idx=i; idx < NZ; idx += 131072) zbase[idx] = z;
  for (int idx=i; idx < G3*H; idx += 131072) wih0f16[idx] = f2h(wih[idx]);
  if (i < B*H){ h0i[i] = f2h(h0in[i]); h1i[i] = f2h(h0in[B*H + i]); }
}

// ---------------- k1: gx0 GEMM  (out layout [t][gate][u][b] f16) ----------------
__global__ __launch_bounds__(256) void k1_gx(const float* __restrict__ x,
                                             const u16* __restrict__ wih0,
                                             const float* __restrict__ bih0,
                                             u16* __restrict__ gxT){
  int t  = blockIdx.x / 6, nb = blockIdx.x % 6;
  int wave = threadIdx.x >> 6, lane = threadIdx.x & 63;
  int l15 = lane & 15, lk = lane >> 4;
  int colbase = nb*256 + wave*64;
  f32x4 acc[2][4] = {};
#pragma unroll 4
  for (int kk=0; kk<16; kk++){
    int k0 = kk*32 + lk*8;
    f16x8 a[2];
#pragma unroll
    for (int bm=0; bm<2; bm++){
      const f32x4* xp = (const f32x4*)(x + ((size_t)(bm*16+l15)*T + t)*H + k0);
      f32x4 x0 = xp[0], x1 = xp[1];
      f16x8 v;
#pragma unroll
      for (int q=0;q<4;q++){ v[q] = (_Float16)x0[q]; v[4+q] = (_Float16)x1[q]; }
      a[bm] = v;
    }
#pragma unroll
    for (int nt=0; nt<4; nt++){
      int col = colbase + nt*16 + l15;
      f16x8 bf = *(const f16x8*)(wih0 + (size_t)col*H + k0);
      acc[0][nt] = MFMA16(a[0], bf, acc[0][nt]);
      acc[1][nt] = MFMA16(a[1], bf, acc[1][nt]);
    }
  }
#pragma unroll
  for (int nt=0; nt<4; nt++){
    int col = colbase + nt*16 + l15;
    float bias = bih0[col];
#pragma unroll
    for (int bm=0; bm<2; bm++){
      u32 lo = (u32)f2h(acc[bm][nt][0]+bias) | ((u32)f2h(acc[bm][nt][1]+bias) << 16);
      u32 hi = (u32)f2h(acc[bm][nt][2]+bias) | ((u32)f2h(acc[bm][nt][3]+bias) << 16);
      u32x2 v; v[0] = lo; v[1] = hi;
      *(u32x2*)(gxT + ((size_t)t*G3 + col)*B + bm*16 + lk*4) = v;
    }
  }
}

// ---------------- k2: persistent recurrence ----------------
__global__ __launch_bounds__(256,1) void k2_recur(const float* __restrict__ h0in,
                                                  const float* __restrict__ Wih,
                                                  const float* __restrict__ bih,
                                                  const float* __restrict__ Whh,
                                                  const float* __restrict__ bhh,
                                                  const u16* __restrict__ gxT,
                                                  u32* __restrict__ h0u,
                                                  u32* __restrict__ h1r,
                                                  const u16* __restrict__ h0i,
                                                  const u16* __restrict__ h1i,
                                                  float* __restrict__ h1fin,
                                                  u32* __restrict__ can){
  __shared__ __align__(16) float part[2][2][64][12];   // [buf][bm][lane][xR xU xN]
  const int wg  = blockIdx.x;
  const int tid = threadIdx.x;
  const int wave = tid >> 6, lane = tid & 63;
  const int l15 = lane & 15, lk = lane >> 4;
  u32* canA = can;                       // [t][64]
  u32* canB = can + (size_t)64*1024;

  if (wg < 16){
    // ===================== layer 0 (A): 4 waves = (bm, ntg) =====================
    const int u0  = wg*32;
    const int bm  = wave >> 1, ntg = wave & 1;
    const int cu  = u0 + ntg*16 + l15;
    const int waveid = wg*4 + wave;
    f16x8 wf[3][16];
    load_wf(wf, Whh, cu, lk);                       // layer-0 W_hh in registers
    const float bhr = bhh[cu], bhu = bhh[512+cu], bhn = bhh[1024+cu];
    float hown[4];
#pragma unroll
    for (int j=0;j<4;j++) hown[j] = h0in[(size_t)(bm*16 + lk*4 + j)*H + cu];

    // gx prologue (t = 0)
    u32x2 g0, g1, g2;
    {
      const u16* gp = gxT + ((size_t)0*G3 + cu)*B + bm*16 + lk*4;
      g0 = *(const u32x2*)gp;
      g1 = *(const u32x2*)(gp + (size_t)512*B);
      g2 = *(const u32x2*)(gp + (size_t)1024*B);
    }

    for (int t=0; t<T; t++){
      f16x8 af[16];
      if (t == 0){
        const u16* hr = h0i + (size_t)(bm*16 + l15)*H + lk*8;
#pragma unroll
        for (int kk=0; kk<16; kk++) af[kk] = *(const f16x8*)(hr + kk*32);
      } else {
        poll64(canA + (size_t)(t-1)*64, (u32)t, lane);
        const u32* hp = h0u + ((size_t)(t-1)*B + bm*16 + l15)*H + lk*8;
        tag_load16(af, hp, (u32)t * 0x10001u);
      }
      // prefetch gx(t+1) — plain cached loads, drained by next step's poll
      int tn = (t+1 < T) ? (t+1) : t;
      const u16* gp = gxT + ((size_t)tn*G3 + cu)*B + bm*16 + lk*4;
      u32x2 ng0 = *(const u32x2*)gp;
      u32x2 ng1 = *(const u32x2*)(gp + (size_t)512*B);
      u32x2 ng2 = *(const u32x2*)(gp + (size_t)1024*B);

      f32x4 aR{}, aU{}, aN{};
      mm48(aR, aU, aN, af, wf);

      const u32 tago = ((u32)(t+1)) << 16;
#pragma unroll
      for (int j=0;j<4;j++){
        float r = fsig(gxval(g0,j) + aR[j] + bhr);
        float u = fsig(gxval(g1,j) + aU[j] + bhu);
        float n = ftanh(gxval(g2,j) + r*(aN[j] + bhn));
        hown[j] = u*hown[j] + (1.f-u)*n;
        int b = bm*16 + lk*4 + j;
        coh_store_u32(h0u + ((size_t)t*B + b)*H + cu, (u32)f2h(hown[j]) | tago);
      }
      if (lane == 0) coh_store_u32(canA + (size_t)t*64 + waveid, (u32)(t+1));
      g0 = ng0; g1 = ng1; g2 = ng2;
    }
  } else {
    // ===================== layer 1 (B): waves 0,1 = x-side; 2,3 = h-side =====================
    const int wg2 = wg - 16;
    const int u0  = wg2*16;
    const int cu  = u0 + l15;
    const bool isX = (wave < 2);
    const int bm  = isX ? wave : (wave - 2);

    if (isX){
      f16x8 wf[3][16];
      load_wf(wf, Wih + (size_t)G3*H, cu, lk);      // layer-1 W_ih in registers
      for (int t=0; t<T; t++){
        poll64(canA + (size_t)t*64, (u32)(t+1), lane);
        f16x8 ax[16];
        const u32* hp = h0u + ((size_t)t*B + bm*16 + l15)*H + lk*8;
        tag_load16(ax, hp, (u32)(t+1) * 0x10001u);
        f32x4 xR{}, xU{}, xN{};
        mm48(xR, xU, xN, ax, wf);
        float* pp = &part[t&1][bm][lane][0];
        *(f32x4*)(pp+0) = xR; *(f32x4*)(pp+4) = xU; *(f32x4*)(pp+8) = xN;
        __syncthreads();
      }
    } else {
      f16x8 wf[3][16];
      load_wf(wf, Whh + (size_t)G3*H, cu, lk);      // layer-1 W_hh in registers
      const int waveid = wg2*2 + bm;
      const float br  = bih[G3 + cu]        + bhh[G3 + cu];
      const float bu  = bih[G3 + 512 + cu]  + bhh[G3 + 512 + cu];
      const float bni = bih[G3 + 1024 + cu];
      const float bnh = bhh[G3 + 1024 + cu];
      float hown[4];
#pragma unroll
      for (int j=0;j<4;j++) hown[j] = h0in[(size_t)B*H + (size_t)(bm*16 + lk*4 + j)*H + cu];

      for (int t=0; t<T; t++){
        f16x8 ah[16];
        if (t == 0){
          const u16* hr = h1i + (size_t)(bm*16 + l15)*H + lk*8;
#pragma unroll
          for (int kk=0; kk<16; kk++) ah[kk] = *(const f16x8*)(hr + kk*32);
        } else {
          poll64(canB + (size_t)(t-1)*64, (u32)t, lane);
          const u32* hp = h1r + ((size_t)((t-1)&7)*B + bm*16 + l15)*H + lk*8;
          tag_load16(ah, hp, (u32)t * 0x10001u);
        }
        f32x4 hR{}, hU{}, hN{};
        mm48(hR, hU, hN, ah, wf);
        __syncthreads();
        const float* pp = &part[t&1][bm][lane][0];
        f32x4 xR = *(const f32x4*)(pp+0);
        f32x4 xU = *(const f32x4*)(pp+4);
        f32x4 xN = *(const f32x4*)(pp+8);

        const u32 tago = ((u32)(t+1)) << 16;
#pragma unroll
        for (int j=0;j<4;j++){
          float r = fsig(xR[j] + hR[j] + br);
          float u = fsig(xU[j] + hU[j] + bu);
          float n = ftanh(xN[j] + bni + r*(hN[j] + bnh));
          hown[j] = u*hown[j] + (1.f-u)*n;
          int b = bm*16 + lk*4 + j;
          coh_store_u32(h1r + ((size_t)(t&7)*B + b)*H + cu, (u32)f2h(hown[j]) | tago);
          if (t == T-1) h1fin[(size_t)b*H + cu] = hown[j];
        }
        if (lane == 0) coh_store_u32(canB + (size_t)t*64 + waveid, (u32)(t+1));
      }
    }
  }
}

// ---------------- k3: FC ----------------
__global__ __launch_bounds__(256) void k3_fc(const float* __restrict__ h1fin,
                                             const float* __restrict__ fcW,
                                             const float* __restrict__ fcb,
                                             float* __restrict__ out){
  int g = blockIdx.x*256 + threadIdx.x;     // 16384
  int b = g >> 9, o = g & 511;
  const f32x4* w = (const f32x4*)(fcW + (size_t)o*H);
  const f32x4* h = (const f32x4*)(h1fin + (size_t)b*H);
  float acc = fcb[o];
#pragma unroll 4
  for (int k=0;k<128;k++){
    f32x4 wv = w[k], hv = h[k];
    acc += wv[0]*hv[0] + wv[1]*hv[1] + wv[2]*hv[2] + wv[3]*hv[3];
  }
  out[g] = acc;
}

extern "C" void kernel_launch(void* const* d_in, const int* in_sizes, int n_in,
                              void* d_out, int out_size, void* d_ws, size_t ws_size,
                              hipStream_t stream) {
  const float* x    = (const float*)d_in[0];
  const float* h0   = (const float*)d_in[1];
  const float* Wih  = (const float*)d_in[2];
  const float* bihv = (const float*)d_in[3];
  const float* Whh  = (const float*)d_in[4];
  const float* bhhv = (const float*)d_in[5];
  const float* fcW  = (const float*)d_in[6];
  const float* fcb  = (const float*)d_in[7];
  float* out = (float*)d_out;

  char* ws = (char*)d_ws;
  u16* gxT     = (u16*)(ws + OFF_GX0);
  u32* h0u     = (u32*)(ws + OFF_H0ALL);
  u32* h1r     = (u32*)(ws + OFF_H1RING);
  u32* can     = (u32*)(ws + OFF_CAN);
  u16* wih0f16 = (u16*)(ws + OFF_WIH0);
  u16* h0i     = (u16*)(ws + OFF_H0I);
  u16* h1i     = (u16*)(ws + OFF_H1I);
  float* h1fin = (float*)(ws + OFF_H1F);

  k0_prep<<<512, 256, 0, stream>>>(Wih, h0, wih0f16, h0i, h1i, (u32x4*)(ws + OFF_H0ALL));
  k1_gx<<<T*6, 256, 0, stream>>>(x, wih0f16, bihv, gxT);
  k2_recur<<<48, 256, 0, stream>>>(h0, Wih, bihv, Whh, bhhv,
                                   gxT, h0u, h1r, h0i, h1i, h1fin, can);
  k3_fc<<<64, 256, 0, stream>>>(h1fin, fcW, fcb, out);
}

// Round 6
// 7249.847 us; speedup vs baseline: 1.2109x; 1.2109x over previous
//
#include <hip/hip_runtime.h>
#include <hip/hip_bf16.h>

// GRU: L=2, B=32, T=1024, H=512, OUT=512
// Round 6: lean LLC spine, proven primitives only (no XCD claiming, no atomics).
//   A (WG 0..15):  layer-0 spine. W_hh0 in regs. h0all T-deep. Never waits.
//   X (WG 32..95): layer-1 x-side, 4 t-parities, xpart T-deep (f16, +b_ih1).
//   B (WG 16..31): layer-1 h-side spine. ONE merged poll per step
//                  (canB peers + single canX word), W_hh1 in regs, h1 ring[4].
// All cross-WG data: sc0 sc1 stores, vmcnt(0) drain, then canary (R2-proven).

typedef _Float16 f16x8 __attribute__((ext_vector_type(8)));
typedef float f32x4 __attribute__((ext_vector_type(4)));
typedef unsigned short u16;
typedef unsigned int u32;
typedef u32 u32x2 __attribute__((ext_vector_type(2)));

#define MFMA16(a,b,c) __builtin_amdgcn_mfma_f32_16x16x32_f16((a),(b),(c),0,0,0)
#define SB0 __builtin_amdgcn_sched_barrier(0)
#define VMC(N) asm volatile("s_waitcnt vmcnt(" #N ")" ::: "memory")

static constexpr int B = 32, T = 1024, H = 512, G3 = 1536;

// ws layout (bytes)
static constexpr size_t OFF_GX  = 0;                               // 96MB f16 [t][g*512+u][b]
static constexpr size_t OFF_XP  = OFF_GX + (size_t)T*G3*B*2;       // 96MB f16 [t][g*512+u][b]
static constexpr size_t OFF_H0  = OFF_XP + (size_t)T*G3*B*2;       // 32MB f16 [t][b][u]
static constexpr size_t OFF_H1R = OFF_H0 + (size_t)T*B*H*2;        // 128KB f16 [4][b][u]
static constexpr size_t OFF_CA  = OFF_H1R + (size_t)4*B*H*2;       // 256KB u32 [T][64]
static constexpr size_t OFF_CX  = OFF_CA + (size_t)T*64*4;         // 256KB
static constexpr size_t OFF_CB  = OFF_CX + (size_t)T*64*4;         // 256KB
static constexpr size_t OFF_W0  = OFF_CB + (size_t)T*64*4;         // 1.5MB f16
static constexpr size_t OFF_H0I = OFF_W0 + (size_t)G3*H*2;         // 32KB f16
static constexpr size_t OFF_H1I = OFF_H0I + (size_t)B*H*2;         // 32KB f16
static constexpr size_t OFF_H1F = OFF_H1I + (size_t)B*H*2;         // 64KB f32

__device__ __forceinline__ u16 f2h(float x){ _Float16 h=(_Float16)x; return __builtin_bit_cast(u16,h); }
__device__ __forceinline__ float h2f(u16 u){ _Float16 h=__builtin_bit_cast(_Float16,u); return (float)h; }

// ---- device-scope (LLC) primitives — R2-proven semantics ----
__device__ __forceinline__ u32 llc_poll(const u32* p){
  u32 r; asm volatile("global_load_dword %0, %1, off sc0 sc1\n\ts_waitcnt vmcnt(0)"
                      : "=v"(r) : "v"(p) : "memory"); return r;
}
__device__ __forceinline__ f16x8 llc_ld16(const u16* p){   // no wait
  f16x8 r; asm volatile("global_load_dwordx4 %0, %1, off sc0 sc1" : "=v"(r) : "v"(p)); return r;
}
__device__ __forceinline__ u32x2 llc_ld8(const u16* p){    // no wait
  u32x2 r; asm volatile("global_load_dwordx2 %0, %1, off sc0 sc1" : "=v"(r) : "v"(p)); return r;
}
__device__ __forceinline__ f16x8 pl_ld16(const u16* p){    // plain, no wait
  f16x8 r; asm volatile("global_load_dwordx4 %0, %1, off" : "=v"(r) : "v"(p)); return r;
}
__device__ __forceinline__ u32x2 pl_ld8(const u16* p){     // plain, no wait
  u32x2 r; asm volatile("global_load_dwordx2 %0, %1, off" : "=v"(r) : "v"(p)); return r;
}
__device__ __forceinline__ void llc_st16(u16* p, u32 v){
  asm volatile("global_store_short %0, %1, off sc0 sc1" :: "v"(p), "v"(v) : "memory");
}
__device__ __forceinline__ void llc_st8(u16* p, u32x2 v){
  asm volatile("global_store_dwordx2 %0, %1, off sc0 sc1" :: "v"(p), "v"(v) : "memory");
}
__device__ __forceinline__ void llc_st32(u32* p, u32 v){
  asm volatile("global_store_dword %0, %1, off sc0 sc1" :: "v"(p), "v"(v) : "memory");
}

// 32-entry canary row poll (lanes 32..63 mirror 0..31)
__device__ __forceinline__ void poll32(const u32* row, u32 want, int lane){
  const u32* p = row + (lane & 31);
  while (!__all(llc_poll(p) >= want)) {}
}
// merged: lanes<32 watch rowB[lane] >= wantB; lanes>=32 watch single word *wx >= wantX
__device__ __forceinline__ void pollBX(const u32* rowB, u32 wantB,
                                       const u32* wx, u32 wantX, int lane){
  const u32* p = (lane < 32) ? (rowB + lane) : wx;
  u32 want = (lane < 32) ? wantB : wantX;
  while (!__all(llc_poll(p) >= want)) {}
}

__device__ __forceinline__ float fsig(float x){ return 1.f/(1.f+__expf(-x)); }
__device__ __forceinline__ float ftanh(float x){
  x = fminf(15.f, fmaxf(-15.f, x));
  float e = __expf(-2.f*x);
  return (1.f-e)/(1.f+e);
}
__device__ __forceinline__ float gxval(u32x2 g, int j){
  u32 w = (j & 2) ? g[1] : g[0];
  return h2f((u16)(w >> ((j & 1) * 16)));
}

// W fragments (f32 -> f16) into registers; rows gate*512+cu, cols kk*32+lk*8
__device__ __forceinline__ void load_wf(f16x8 (*wf)[16], const float* Wbase, int cu, int lk){
#pragma unroll
  for (int g=0; g<3; g++)
#pragma unroll
    for (int kk=0; kk<16; kk++){
      const float* s = Wbase + ((size_t)(g*512 + cu))*H + kk*32 + lk*8;
      f32x4 s0 = *(const f32x4*)s, s1 = *(const f32x4*)(s+4);
      f16x8 v;
#pragma unroll
      for (int e=0; e<4; e++){ v[e]=(_Float16)s0[e]; v[4+e]=(_Float16)s1[e]; }
      wf[g][kk] = v;
    }
}

// ---------------- k0: prep ----------------
__global__ __launch_bounds__(256) void k0_prep(const float* __restrict__ wih,
                                               const float* __restrict__ h0in,
                                               u16* __restrict__ wih0f16,
                                               u16* __restrict__ h0i,
                                               u16* __restrict__ h1i,
                                               u32* __restrict__ cans){
  int i = blockIdx.x*256 + threadIdx.x;                  // 65536 threads
  for (int idx=i; idx<G3*H; idx+=65536) wih0f16[idx] = f2h(wih[idx]);
  for (int idx=i; idx<3*T*64; idx+=65536) cans[idx] = 0; // canA|canX|canB
  if (i < B*H){ h0i[i] = f2h(h0in[i]); h1i[i] = f2h(h0in[B*H + i]); }
}

// ---------------- k1: gx0 GEMM  (out [t][gate][u][b] f16) ----------------
__global__ __launch_bounds__(256) void k1_gx(const float* __restrict__ x,
                                             const u16* __restrict__ wih0,
                                             const float* __restrict__ bih0,
                                             u16* __restrict__ gxT){
  int t  = blockIdx.x / 6, nb = blockIdx.x % 6;
  int wave = threadIdx.x >> 6, lane = threadIdx.x & 63;
  int l15 = lane & 15, lk = lane >> 4;
  int colbase = nb*256 + wave*64;
  f32x4 acc[2][4] = {};
#pragma unroll 4
  for (int kk=0; kk<16; kk++){
    int k0 = kk*32 + lk*8;
    f16x8 a[2];
#pragma unroll
    for (int bm=0; bm<2; bm++){
      const f32x4* xp_ = (const f32x4*)(x + ((size_t)(bm*16+l15)*T + t)*H + k0);
      f32x4 x0 = xp_[0], x1 = xp_[1];
      f16x8 v;
#pragma unroll
      for (int q=0;q<4;q++){ v[q]=(_Float16)x0[q]; v[4+q]=(_Float16)x1[q]; }
      a[bm] = v;
    }
#pragma unroll
    for (int nt=0; nt<4; nt++){
      int col = colbase + nt*16 + l15;
      f16x8 bf = *(const f16x8*)(wih0 + (size_t)col*H + k0);
      acc[0][nt] = MFMA16(a[0], bf, acc[0][nt]);
      acc[1][nt] = MFMA16(a[1], bf, acc[1][nt]);
    }
  }
#pragma unroll
  for (int nt=0; nt<4; nt++){
    int col = colbase + nt*16 + l15;
    float bias = bih0[col];
#pragma unroll
    for (int bm=0; bm<2; bm++){
      u32 lo = (u32)f2h(acc[bm][nt][0]+bias) | ((u32)f2h(acc[bm][nt][1]+bias) << 16);
      u32 hi = (u32)f2h(acc[bm][nt][2]+bias) | ((u32)f2h(acc[bm][nt][3]+bias) << 16);
      u32x2 v; v[0]=lo; v[1]=hi;
      *(u32x2*)(gxT + ((size_t)t*G3 + col)*B + bm*16 + lk*4) = v;
    }
  }
}

// ---------------- k2: persistent recurrence (96 WGs, no LDS) ----------------
__global__ __launch_bounds__(256,1) void k2_recur(const float* __restrict__ h0in,
    const float* __restrict__ Wih, const float* __restrict__ bih,
    const float* __restrict__ Whh, const float* __restrict__ bhh,
    const u16* __restrict__ gxT, u16* __restrict__ xp,
    u16* __restrict__ h0all, u16* __restrict__ h1r,
    u32* __restrict__ canA, u32* __restrict__ canX, u32* __restrict__ canB,
    const u16* __restrict__ h0i, const u16* __restrict__ h1i,
    float* __restrict__ h1fin)
{
  const int wg = blockIdx.x, tid = threadIdx.x;
  const int wave = tid >> 6, lane = tid & 63;
  const int l15 = lane & 15, lk = lane >> 4;
  const int bm = wave >> 1, ug = wave & 1;

  if (wg < 16){
    // ================= A: layer-0 spine =================
    const int slot = wg;
    const int cu   = slot*32 + ug*16 + l15;
    const int cwid = bm*32 + slot*2 + ug;
    f16x8 wf[3][16]; load_wf(wf, Whh, cu, lk);
    const float bhr = bhh[cu], bhu = bhh[512+cu], bhn = bhh[1024+cu];
    float hown[4];
#pragma unroll
    for (int j=0;j<4;j++) hown[j] = h0in[(size_t)(bm*16+lk*4+j)*H + cu];

    // gx(0) prologue
    u32x2 g0, g1, g2;
    { const u16* gp = gxT + ((size_t)0*G3 + cu)*B + bm*16 + lk*4;
      g0 = pl_ld8(gp); g1 = pl_ld8(gp + (size_t)512*B); g2 = pl_ld8(gp + (size_t)1024*B); }
    VMC(0); SB0;

    for (int t=0; t<T; t++){
      if (t > 0){ poll32(canA + (size_t)(t-1)*64 + bm*32, (u32)t, lane); SB0; }
      f16x8 af[16];
      if (t == 0){
        const u16* hr = h0i + (size_t)(bm*16+l15)*H + lk*8;
#pragma unroll
        for (int kk=0; kk<16; kk++) af[kk] = pl_ld16(hr + kk*32);
      } else {
        const u16* hr = h0all + ((size_t)(t-1)*B + bm*16 + l15)*H + lk*8;
#pragma unroll
        for (int kk=0; kk<16; kk++) af[kk] = llc_ld16(hr + kk*32);
      }
      VMC(0); SB0;
      f32x4 aR{}, aU{}, aN{};
#pragma unroll
      for (int kk=0; kk<16; kk++){
        aR = MFMA16(af[kk], wf[0][kk], aR);
        aU = MFMA16(af[kk], wf[1][kk], aU);
        aN = MFMA16(af[kk], wf[2][kk], aN);
      }
#pragma unroll
      for (int j=0;j<4;j++){
        float r = fsig(gxval(g0,j) + aR[j] + bhr);
        float u = fsig(gxval(g1,j) + aU[j] + bhu);
        float n = ftanh(gxval(g2,j) + r*(aN[j] + bhn));
        hown[j] = u*hown[j] + (1.f-u)*n;
        llc_st16(h0all + ((size_t)t*B + bm*16+lk*4+j)*H + cu, (u32)f2h(hown[j]));
      }
      VMC(0);
      if (lane == 0) llc_st32(canA + (size_t)t*64 + cwid, (u32)(t+1));
      if (t+1 < T){
        const u16* gp = gxT + ((size_t)(t+1)*G3 + cu)*B + bm*16 + lk*4;
        g0 = pl_ld8(gp); g1 = pl_ld8(gp + (size_t)512*B); g2 = pl_ld8(gp + (size_t)1024*B);
        // drained by next iteration's poll (vmcnt(0) inside llc_poll)
      }
    }
  } else if (wg < 32){
    // ================= B: layer-1 h-side spine =================
    const int slot = wg - 16;
    const int cu   = slot*32 + ug*16 + l15;
    const int cwid = bm*32 + slot*2 + ug;
    f16x8 wf[3][16]; load_wf(wf, Whh + (size_t)G3*H, cu, lk);
    const float bhr = bhh[G3 + cu], bhu = bhh[G3 + 512 + cu], bhn = bhh[G3 + 1024 + cu];
    float hown[4];
#pragma unroll
    for (int j=0;j<4;j++) hown[j] = h0in[(size_t)B*H + (size_t)(bm*16+lk*4+j)*H + cu];

    for (int t=0; t<T; t++){
      const u32* rowB = canB + (size_t)(t ? (t-1) : 0)*64 + bm*32;
      const u32* wx   = canX + (size_t)t*64 + cwid;
      pollBX(rowB, (u32)t, wx, (u32)(t+1), lane); SB0;

      f16x8 ah[16];
      if (t == 0){
        const u16* hr = h1i + (size_t)(bm*16+l15)*H + lk*8;
#pragma unroll
        for (int kk=0; kk<16; kk++) ah[kk] = pl_ld16(hr + kk*32);
      } else {
        const u16* hr = h1r + ((size_t)((t-1)&3)*B + bm*16 + l15)*H + lk*8;
#pragma unroll
        for (int kk=0; kk<16; kk++) ah[kk] = llc_ld16(hr + kk*32);
      }
      u32x2 x0, x1, x2;
      { const u16* xb = xp + ((size_t)t*G3 + cu)*B + bm*16 + lk*4;
        x0 = llc_ld8(xb); x1 = llc_ld8(xb + (size_t)512*B); x2 = llc_ld8(xb + (size_t)1024*B); }
      VMC(3); SB0;                       // 16 h loads done; 3 xp outstanding
      f32x4 hR{}, hU{}, hN{};
#pragma unroll
      for (int kk=0; kk<16; kk++){
        hR = MFMA16(ah[kk], wf[0][kk], hR);
        hU = MFMA16(ah[kk], wf[1][kk], hU);
        hN = MFMA16(ah[kk], wf[2][kk], hN);
      }
      VMC(0); SB0;                       // xp ready
#pragma unroll
      for (int j=0;j<4;j++){
        float r = fsig(gxval(x0,j) + hR[j] + bhr);
        float u = fsig(gxval(x1,j) + hU[j] + bhu);
        float n = ftanh(gxval(x2,j) + r*(hN[j] + bhn));
        hown[j] = u*hown[j] + (1.f-u)*n;
        int b = bm*16 + lk*4 + j;
        llc_st16(h1r + ((size_t)(t&3)*B + b)*H + cu, (u32)f2h(hown[j]));
        if (t == T-1) h1fin[(size_t)b*H + cu] = hown[j];
      }
      VMC(0);
      if (lane == 0) llc_st32(canB + (size_t)t*64 + cwid, (u32)(t+1));
    }
  } else {
    // ================= X: layer-1 x-side (4 t-parities) =================
    const int xi = wg - 32;
    const int slot = xi & 15, parity = xi >> 4;          // 16 slots x 4 parities
    const int cu   = slot*32 + ug*16 + l15;
    const int cwid = bm*32 + slot*2 + ug;
    f16x8 wf[3][16]; load_wf(wf, Wih + (size_t)G3*H, cu, lk);
    const float br = bih[G3 + cu], bu = bih[G3 + 512 + cu], bn = bih[G3 + 1024 + cu];

    for (int t = parity; t < T; t += 4){
      poll32(canA + (size_t)t*64 + bm*32, (u32)(t+1), lane); SB0;
      f16x8 ax[16];
      const u16* hr = h0all + ((size_t)t*B + bm*16 + l15)*H + lk*8;
#pragma unroll
      for (int kk=0; kk<16; kk++) ax[kk] = llc_ld16(hr + kk*32);
      VMC(0); SB0;
      f32x4 xR{}, xU{}, xN{};
#pragma unroll
      for (int kk=0; kk<16; kk++){
        xR = MFMA16(ax[kk], wf[0][kk], xR);
        xU = MFMA16(ax[kk], wf[1][kk], xU);
        xN = MFMA16(ax[kk], wf[2][kk], xN);
      }
      u16* xb = xp + ((size_t)t*G3 + cu)*B + bm*16 + lk*4;
      u32x2 v0, v1, v2;
      v0[0] = (u32)f2h(xR[0]+br) | ((u32)f2h(xR[1]+br) << 16);
      v0[1] = (u32)f2h(xR[2]+br) | ((u32)f2h(xR[3]+br) << 16);
      v1[0] = (u32)f2h(xU[0]+bu) | ((u32)f2h(xU[1]+bu) << 16);
      v1[1] = (u32)f2h(xU[2]+bu) | ((u32)f2h(xU[3]+bu) << 16);
      v2[0] = (u32)f2h(xN[0]+bn) | ((u32)f2h(xN[1]+bn) << 16);
      v2[1] = (u32)f2h(xN[2]+bn) | ((u32)f2h(xN[3]+bn) << 16);
      llc_st8(xb, v0);
      llc_st8(xb + (size_t)512*B, v1);
      llc_st8(xb + (size_t)1024*B, v2);
      VMC(0);
      if (lane == 0) llc_st32(canX + (size_t)t*64 + cwid, (u32)(t+1));
    }
  }
}

// ---------------- k3: FC ----------------
__global__ __launch_bounds__(256) void k3_fc(const float* __restrict__ h1fin,
                                             const float* __restrict__ fcW,
                                             const float* __restrict__ fcb,
                                             float* __restrict__ out){
  int g = blockIdx.x*256 + threadIdx.x;     // 16384
  int b = g >> 9, o = g & 511;
  const f32x4* w = (const f32x4*)(fcW + (size_t)o*H);
  const f32x4* h = (const f32x4*)(h1fin + (size_t)b*H);
  float acc = fcb[o];
#pragma unroll 4
  for (int k=0;k<128;k++){
    f32x4 wv = w[k], hv = h[k];
    acc += wv[0]*hv[0] + wv[1]*hv[1] + wv[2]*hv[2] + wv[3]*hv[3];
  }
  out[g] = acc;
}

extern "C" void kernel_launch(void* const* d_in, const int* in_sizes, int n_in,
                              void* d_out, int out_size, void* d_ws, size_t ws_size,
                              hipStream_t stream) {
  const float* x    = (const float*)d_in[0];
  const float* h0   = (const float*)d_in[1];
  const float* Wih  = (const float*)d_in[2];
  const float* bihv = (const float*)d_in[3];
  const float* Whh  = (const float*)d_in[4];
  const float* bhhv = (const float*)d_in[5];
  const float* fcW  = (const float*)d_in[6];
  const float* fcb  = (const float*)d_in[7];
  float* out = (float*)d_out;

  char* ws = (char*)d_ws;
  u16* gxT     = (u16*)(ws + OFF_GX);
  u16* xp      = (u16*)(ws + OFF_XP);
  u16* h0all   = (u16*)(ws + OFF_H0);
  u16* h1r     = (u16*)(ws + OFF_H1R);
  u32* canA    = (u32*)(ws + OFF_CA);
  u32* canX    = (u32*)(ws + OFF_CX);
  u32* canB    = (u32*)(ws + OFF_CB);
  u16* wih0f16 = (u16*)(ws + OFF_W0);
  u16* h0i     = (u16*)(ws + OFF_H0I);
  u16* h1i     = (u16*)(ws + OFF_H1I);
  float* h1fin = (float*)(ws + OFF_H1F);

  k0_prep<<<256, 256, 0, stream>>>(Wih, h0, wih0f16, h0i, h1i, canA);
  k1_gx<<<T*6, 256, 0, stream>>>(x, wih0f16, bihv, gxT);
  k2_recur<<<96, 256, 0, stream>>>(h0, Wih, bihv, Whh, bhhv, gxT, xp,
                                   h0all, h1r, canA, canX, canB,
                                   h0i, h1i, h1fin);
  k3_fc<<<64, 256, 0, stream>>>(h1fin, fcW, fcb, out);
}